// Round 7
// baseline (1449.272 us; speedup 1.0000x reference)
//
#include <hip/hip_runtime.h>
#include <math.h>

// Restarted GMRES(16), 4 cycles, Helmholtz (-lap + 0.3) on 1024x1024 periodic fp32.
// Round 7: ONE grid barrier per Arnoldi step (68 total, was 131). Register halo-V
// history (hv[16] pairs/thread, bit-identical to neighbor's values) lets each block
// build the stencil halo of w3 locally. Block-0 reduces partial columns inside the
// barrier (others poll anyway); b64-packed edge atomics; halo staged via LDS and
// lf/rt via shfl (no uncached loads, no bank-conflict scalars in the stencil).

#define NGRID 1024
#define NE (NGRID*NGRID)
#define NB 256            // blocks = CUs
#define TPB 1024          // 16 waves
#define RST 16
#define KMAX 17
#define NCYC 4
#define FLAG_STRIDE 16
#define ESZ (NB*2*NGRID)  // floats per edge-buffer parity

__device__ __forceinline__ float4 ld4(const float* p){return *reinterpret_cast<const float4*>(p);}
__device__ __forceinline__ void st4(float* p, float4 v){*reinterpret_cast<float4*>(p)=v;}
__device__ __forceinline__ float dot4(float4 a,float4 b){return a.x*b.x+a.y*b.y+a.z*b.z+a.w*b.w;}

// IC-coherent accesses (relaxed agent-scope atomics)
__device__ __forceinline__ float ldc(const float* p){
  return __hip_atomic_load(p, __ATOMIC_RELAXED, __HIP_MEMORY_SCOPE_AGENT);
}
__device__ __forceinline__ void stc(float* p, float v){
  __hip_atomic_store(p, v, __ATOMIC_RELAXED, __HIP_MEMORY_SCOPE_AGENT);
}
__device__ __forceinline__ int ldci(const int* p){
  return __hip_atomic_load(p, __ATOMIC_RELAXED, __HIP_MEMORY_SCOPE_AGENT);
}
__device__ __forceinline__ void stci(int* p, int v){
  __hip_atomic_store(p, v, __ATOMIC_RELAXED, __HIP_MEMORY_SCOPE_AGENT);
}
__device__ __forceinline__ void stc64(float* p, float a, float b){
  unsigned long long v = ((unsigned long long)__float_as_uint(b) << 32)
                       | (unsigned long long)__float_as_uint(a);
  __hip_atomic_store(reinterpret_cast<unsigned long long*>(p), v,
                     __ATOMIC_RELAXED, __HIP_MEMORY_SCOPE_AGENT);
}
__device__ __forceinline__ float2 ldc64(const float* p){
  unsigned long long v = __hip_atomic_load(reinterpret_cast<const unsigned long long*>(p),
                                           __ATOMIC_RELAXED, __HIP_MEMORY_SCOPE_AGENT);
  return make_float2(__uint_as_float((unsigned)v), __uint_as_float((unsigned)(v>>32)));
}

__device__ __forceinline__ float wave_reduce(float s){
  #pragma unroll
  for(int off=32; off; off>>=1) s += __shfl_down(s,off);
  return s;
}
__device__ __forceinline__ float col_reduce256(const float* col, int lane){
  int b4i = lane*4;
  float s = (ldc(col+b4i) + ldc(col+b4i+1)) + (ldc(col+b4i+2) + ldc(col+b4i+3));
  return wave_reduce(s);
}

// grid barrier with in-barrier central reduce: block0 waits for all flags, reduces
// partial cols [0,nc) (+ norm col 16 if donorm) into pdH, then broadcasts gen.
__device__ __forceinline__ void gridbar(int* arrive, int* gen,
                                        const float* pdA, float* pdH,
                                        int bar_id, int blk, int t, int wv, int lane,
                                        int nc, int donorm){
  __syncthreads();   // per-wave vmcnt drain: all our stc's are at IC before flag
  if (blk == 0) {
    if (t > 0 && t < NB) {
      while (ldci(&arrive[t*FLAG_STRIDE]) < bar_id) __builtin_amdgcn_s_sleep(2);
    }
    __syncthreads();
    for (int c = wv; c < nc; c += 16) {
      float s = col_reduce256(pdA + c*NB, lane);
      if (lane == 0) stc(&pdH[c], s);
    }
    if (donorm && wv == 15) {
      float s = col_reduce256(pdA + 16*NB, lane);
      if (lane == 0) stc(&pdH[16], s);
    }
    __syncthreads();
    if (t == 0) stci(gen, bar_id);
  } else {
    if (t == 0) {
      stci(&arrive[blk*FLAG_STRIDE], bar_id);
      while (ldci(gen) < bar_id) __builtin_amdgcn_s_sleep(2);
    }
    __syncthreads();
  }
}

// stencil over LDS tile + LDS halo rows; lf/rt via shfl of raw center values.
// center c already scaled by inv; raw = unscaled center; neighbors scaled inside.
__device__ __forceinline__ float4 stencil2(float4 raw, float4 c, float inv,
                                           const float (*wt)[NGRID],
                                           const float* hup, const float* hdn,
                                           int lr, int cq, int lane){
  float4 a, d;
  if (lr == 0) a = ld4(hup + cq);           else a = ld4(&wt[lr-1][cq]);
  if (lr == 3) d = ld4(hdn + cq);           else d = ld4(&wt[lr+1][cq]);
  float lf = __shfl_up(raw.w, 1);
  float rt = __shfl_down(raw.x, 1);
  if (lane == 0)  lf = wt[lr][(cq + NGRID-1) & (NGRID-1)];
  if (lane == 63) rt = wt[lr][(cq + 4) & (NGRID-1)];
  lf *= inv; rt *= inv;
  a.x*=inv; a.y*=inv; a.z*=inv; a.w*=inv;
  d.x*=inv; d.y*=inv; d.z*=inv; d.w*=inv;
  float4 o;
  o.x = 0.3f*c.x - ((a.x + d.x + lf  + c.y) - 4.0f*c.x);
  o.y = 0.3f*c.y - ((a.y + d.y + c.x + c.z) - 4.0f*c.y);
  o.z = 0.3f*c.z - ((a.z + d.z + c.y + c.w) - 4.0f*c.z);
  o.w = 0.3f*c.w - ((a.w + d.w + c.z + rt ) - 4.0f*c.w);
  return o;
}

// plain global stencil (cycle-0 residual on pristine guess)
__device__ __forceinline__ float4 stencil_g(const float* __restrict__ u,
                                            float4 c, int gi, int cq){
  const float* up = u + (((gi+NGRID-1)&(NGRID-1))<<10);
  const float* dn = u + (((gi+1)&(NGRID-1))<<10);
  float4 a = ld4(up+cq), d = ld4(dn+cq);
  float lf = u[(gi<<10)|((cq+NGRID-1)&(NGRID-1))];
  float rt = u[(gi<<10)|((cq+4)&(NGRID-1))];
  float4 o;
  o.x = 0.3f*c.x - ((a.x + d.x + lf  + c.y) - 4.0f*c.x);
  o.y = 0.3f*c.y - ((a.y + d.y + c.x + c.z) - 4.0f*c.y);
  o.z = 0.3f*c.z - ((a.z + d.z + c.y + c.w) - 4.0f*c.z);
  o.w = 0.3f*c.w - ((a.w + d.w + c.z + rt ) - 4.0f*c.w);
  return o;
}

__global__ __launch_bounds__(TPB, 4) void k_gmres(
    const float* __restrict__ b, const float* __restrict__ guess,
    float* __restrict__ x, float* __restrict__ E,
    float* __restrict__ pdA, float* __restrict__ pdH,
    int* __restrict__ arrive, int* __restrict__ gen)
{
  const int t = threadIdx.x, blk = blockIdx.x;
  const int lr = t >> 8;                 // local row 0..3
  const int cq = (t & 255) << 2;         // col of this thread's 4 elems
  const int gi = blk*4 + lr;
  const int gelem = (gi<<10) + cq;
  const int lane = t & 63, wv = t >> 6;
  const int hcol = (t & 511) << 1;       // this thread's 2 halo cols
  const bool isup = (t < 512);           // owns up-halo (else dn-halo)

  __shared__ float wt[4][NGRID];         // 16 KB staging tile
  __shared__ float hrow[2][NGRID];       // raw halo rows: [0]=up, [1]=dn
  __shared__ float red[KMAX][16];
  __shared__ float sH[KMAX], sC[KMAX];
  __shared__ float G[KMAX][KMAX];
  __shared__ float Hm[KMAX][RST];
  __shared__ float M[RST][RST+1];
  __shared__ float yv[RST];
  __shared__ float sBeta, sInv;

  float4 x4, w4;
  float4 vcr[RST];
  float2 hv[RST];                        // halo-V history (bit-identical to neighbor's v)
  float2 hx;                             // halo-x
  int bid = 1, rp = 0;

  // edge row pointers (publish side recomputed from rp each use)
  const int uprow = (((blk+NB-1)&(NB-1))<<1) + 1;   // neighbor-above's lr3 row
  const int dnrow = (((blk+1)&(NB-1))<<1);          // neighbor-below's lr0 row

  // ---------------- P_init (cycle 0 residual, pristine inputs, plain loads) ----
  x4 = ld4(guess + gelem);
  {
    int hrg = isup ? ((blk*4 + NGRID-1)&(NGRID-1)) : ((blk*4 + 4)&(NGRID-1));
    hx.x = guess[(hrg<<10) + hcol];
    hx.y = guess[(hrg<<10) + hcol + 1];
  }
  {
    float4 ax = stencil_g(guess, x4, gi, cq);
    float4 b4 = ld4(b + gelem);
    w4.x = b4.x - ax.x; w4.y = b4.y - ax.y; w4.z = b4.z - ax.z; w4.w = b4.w - ax.w;
    st4(&wt[lr][cq], w4);                       // wt <- r (pre0's stencil input)
    float s = wave_reduce(dot4(w4, w4));
    if (lane == 0) red[16][wv] = s;
    __syncthreads();
    if (t == 16) {
      float acc = 0.f;
      #pragma unroll
      for (int q = 0; q < 16; ++q) acc += red[16][q];
      stc(&pdA[16*NB + blk], acc);
    }
    if (lr == 0) { float* er = E + (rp^1)*ESZ + ((blk<<1)<<10);
                   stc64(er+cq, w4.x, w4.y); stc64(er+cq+2, w4.z, w4.w); }
    if (lr == 3) { float* er = E + (rp^1)*ESZ + (((blk<<1)+1)<<10);
                   stc64(er+cq, w4.x, w4.y); stc64(er+cq+2, w4.z, w4.w); }
    gridbar(arrive, gen, pdA, pdH, bid++, blk, t, wv, lane, 0, 1);
    rp ^= 1;
  }

  #pragma unroll 1
  for (int cyc = 0; cyc < NCYC; ++cyc) {
    // ---------------- P_pre0: beta, v0 = r/beta, w = A(v0), first dots ----------
    {
      float pn16 = (t == 0) ? ldc(&pdH[16]) : 0.f;           // early issue
      float2 hw = ldc64((isup ? (E + rp*ESZ + (uprow<<10))
                              : (E + rp*ESZ + (dnrow<<10))) + hcol);  // r edges
      for (int q = t; q < KMAX*KMAX; q += TPB) ((float*)G)[q] = 0.f;
      for (int q = t; q < KMAX*RST;  q += TPB) ((float*)Hm)[q] = 0.f;
      __syncthreads();
      if (t == 0) {
        float beta = sqrtf(pn16);
        sBeta = beta; sInv = 1.0f/(beta + 1e-12f); G[0][0] = 1.0f;
      }
      __syncthreads();
      float inv = sInv;
      vcr[0].x = w4.x*inv; vcr[0].y = w4.y*inv; vcr[0].z = w4.z*inv; vcr[0].w = w4.w*inv;
      hv[0].x = hw.x*inv; hv[0].y = hw.y*inv;
      hrow[isup?0:1][hcol]   = hw.x;                          // raw halo r
      hrow[isup?0:1][hcol+1] = hw.y;
      __syncthreads();
      float4 nw = stencil2(w4, vcr[0], inv, wt, hrow[0], hrow[1], lr, cq, lane);
      w4 = nw;
      { float s = wave_reduce(dot4(vcr[0], w4)); if (lane == 0) red[0][wv] = s; }
      { float s = wave_reduce(dot4(w4, w4));     if (lane == 0) red[16][wv] = s; }
      __syncthreads();
      if (t == 0) { float acc=0.f;
        #pragma unroll
        for (int q=0;q<16;++q) acc += red[0][q];  stc(&pdA[0*NB+blk], acc); }
      if (t == 16){ float acc=0.f;
        #pragma unroll
        for (int q=0;q<16;++q) acc += red[16][q]; stc(&pdA[16*NB+blk], acc); }
      if (lr == 0) { float* er = E + (rp^1)*ESZ + ((blk<<1)<<10);
                     stc64(er+cq, w4.x, w4.y); stc64(er+cq+2, w4.z, w4.w); }
      if (lr == 3) { float* er = E + (rp^1)*ESZ + (((blk<<1)+1)<<10);
                     stc64(er+cq, w4.x, w4.y); stc64(er+cq+2, w4.z, w4.w); }
      gridbar(arrive, gen, pdA, pdH, bid++, blk, t, wv, lane, 1, 1);
      rp ^= 1;
    }

    // ---------------- steps J = 0..14: one barrier each -------------------------
    #pragma unroll
    for (int J = 0; J < RST-1; ++J) {
      float2 hw = ldc64((isup ? (E + rp*ESZ + (uprow<<10))
                              : (E + rp*ESZ + (dnrow<<10))) + hcol);  // w edges
      if (t <= J)   sH[t]  = ldc(&pdH[t]);
      if (t == 16)  sH[16] = ldc(&pdH[16]);
      __syncthreads();
      if (t < 64) {                         // c = 2 h1 - G h1
        int k = t;
        double h1k = (k <= J) ? (double)sH[k] : 0.0;
        double g1k = 0.0;
        for (int m = 0; m <= J; ++m) g1k += (double)G[k][m]*(double)sH[m];
        double ck = 2.0*h1k - g1k;
        if (k <= J) sC[k] = (float)ck;
      }
      __syncthreads();
      if (t < 64) {                         // hn, inv, Hm col J, G col J+1
        int k = t;
        double h1k = (k <= J) ? (double)sH[k] : 0.0;
        double ck  = (k <= J) ? (double)sC[k] : 0.0;
        double gck = 0.0;
        for (int m = 0; m <= J; ++m) gck += (double)G[k][m]*(double)sC[m];
        double part = ck*(gck - 2.0*h1k);
        #pragma unroll
        for (int off = 32; off; off >>= 1) part += __shfl_xor(part, off);
        double hn2 = (double)sH[16] + part;
        double hn = sqrt(hn2 > 0.0 ? hn2 : 0.0);
        if (k == 0) { sInv = (float)(1.0/(hn + 1e-12)); Hm[J+1][J] = (float)hn; }
        if (k <= J) Hm[k][J] = sC[k];
        if (k <= J) { float gn = (float)((h1k - gck)/hn); G[k][J+1] = gn; G[J+1][k] = gn; }
        if (k == 0) G[J+1][J+1] = 1.0f;
      }
      __syncthreads();
      float inv = sInv;
      float4 w3 = w4;
      #pragma unroll
      for (int k = 0; k <= J; ++k) {
        float ck = sC[k];
        w3.x -= ck*vcr[k].x; w3.y -= ck*vcr[k].y; w3.z -= ck*vcr[k].z; w3.w -= ck*vcr[k].w;
      }
      vcr[J+1].x = w3.x*inv; vcr[J+1].y = w3.y*inv; vcr[J+1].z = w3.z*inv; vcr[J+1].w = w3.w*inv;
      st4(&wt[lr][cq], w3);                 // wt <- w3 (raw)
      float2 w3h = hw;
      #pragma unroll
      for (int k = 0; k <= J; ++k) { float ck = sC[k]; w3h.x -= ck*hv[k].x; w3h.y -= ck*hv[k].y; }
      hv[J+1].x = w3h.x*inv; hv[J+1].y = w3h.y*inv;
      hrow[isup?0:1][hcol]   = w3h.x;       // raw halo w3
      hrow[isup?0:1][hcol+1] = w3h.y;
      __syncthreads();
      float4 nw = stencil2(w3, vcr[J+1], inv, wt, hrow[0], hrow[1], lr, cq, lane);
      w4 = nw;                              // w4 = A(v_{J+1})
      #pragma unroll
      for (int k = 0; k <= J+1; ++k) {
        float s = wave_reduce(dot4(vcr[k], w4));
        if (lane == 0) red[k][wv] = s;
      }
      { float s = wave_reduce(dot4(w4, w4)); if (lane == 0) red[16][wv] = s; }
      __syncthreads();
      if (t <= J+1) { float acc=0.f;
        #pragma unroll
        for (int q=0;q<16;++q) acc += red[t][q];  stc(&pdA[t*NB+blk], acc); }
      if (t == 16)  { float acc=0.f;
        #pragma unroll
        for (int q=0;q<16;++q) acc += red[16][q]; stc(&pdA[16*NB+blk], acc); }
      if (lr == 0) { float* er = E + (rp^1)*ESZ + ((blk<<1)<<10);
                     stc64(er+cq, w4.x, w4.y); stc64(er+cq+2, w4.z, w4.w); }
      if (lr == 3) { float* er = E + (rp^1)*ESZ + (((blk<<1)+1)<<10);
                     stc64(er+cq, w4.x, w4.y); stc64(er+cq+2, w4.z, w4.w); }
      gridbar(arrive, gen, pdA, pdH, bid++, blk, t, wv, lane, J+2, 1);
      rp ^= 1;
    }

    // ---------------- P_fin: Hm col 15, solve, x update, residual for next cycle
    {
      const int J = RST-1;  // 15
      if (t <= J)  sH[t]  = ldc(&pdH[t]);
      if (t == 16) sH[16] = ldc(&pdH[16]);
      __syncthreads();
      if (t < 64) {
        int k = t;
        double h1k = (k <= J) ? (double)sH[k] : 0.0;
        double g1k = 0.0;
        for (int m = 0; m <= J; ++m) g1k += (double)G[k][m]*(double)sH[m];
        double ck = 2.0*h1k - g1k;
        if (k <= J) sC[k] = (float)ck;
      }
      __syncthreads();
      if (t < 64) {
        int k = t;
        double h1k = (k <= J) ? (double)sH[k] : 0.0;
        double ck  = (k <= J) ? (double)sC[k] : 0.0;
        double gck = 0.0;
        for (int m = 0; m <= J; ++m) gck += (double)G[k][m]*(double)sC[m];
        double part = ck*(gck - 2.0*h1k);
        #pragma unroll
        for (int off = 32; off; off >>= 1) part += __shfl_xor(part, off);
        double hn2 = (double)sH[16] + part;
        double hn = sqrt(hn2 > 0.0 ? hn2 : 0.0);
        if (k == 0) Hm[J+1][J] = (float)hn;
        if (k <= J) Hm[k][J] = sC[k];
      }
      __syncthreads();
      // 16x16 normal equations
      if (t < 256) {
        int a = t >> 4, bq = t & 15;
        float s = 0.f;
        #pragma unroll
        for (int k = 0; k < KMAX; ++k) s += Hm[k][a]*Hm[k][bq];
        M[a][bq] = s + (a == bq ? 1e-12f : 0.0f);
      }
      __syncthreads();
      if (t < RST) M[t][RST] = sBeta * Hm[0][t];
      __syncthreads();
      for (int c = 0; c < RST; ++c) {
        if (t == 0) {
          int p = c; float mx = fabsf(M[c][c]);
          for (int r = c+1; r < RST; ++r){ float v=fabsf(M[r][c]); if (v>mx){mx=v;p=r;} }
          if (p != c) for (int cc = c; cc <= RST; ++cc){ float tmp=M[c][cc]; M[c][cc]=M[p][cc]; M[p][cc]=tmp; }
        }
        __syncthreads();
        if (t > c && t < RST) {
          float f = M[t][c]/M[c][c];
          for (int cc = c; cc <= RST; ++cc) M[t][cc] -= f*M[c][cc];
        }
        __syncthreads();
      }
      if (t == 0) {
        for (int c = RST-1; c >= 0; --c) {
          float s = M[c][RST];
          for (int cc = c+1; cc < RST; ++cc) s -= M[c][cc]*yv[cc];
          yv[c] = s/M[c][c];
        }
      }
      __syncthreads();
      #pragma unroll
      for (int k = 0; k < RST; ++k) {
        float yk = yv[k];
        x4.x += yk*vcr[k].x; x4.y += yk*vcr[k].y; x4.z += yk*vcr[k].z; x4.w += yk*vcr[k].w;
      }
      st4(x + gelem, x4);

      if (cyc < NCYC-1) {
        // halo-x update (bit-identical to neighbor's x), residual, publish
        #pragma unroll
        for (int k = 0; k < RST; ++k) { float yk = yv[k]; hx.x += yk*hv[k].x; hx.y += yk*hv[k].y; }
        st4(&wt[lr][cq], x4);
        hrow[isup?0:1][hcol]   = hx.x;
        hrow[isup?0:1][hcol+1] = hx.y;
        __syncthreads();
        float4 ax = stencil2(x4, x4, 1.0f, wt, hrow[0], hrow[1], lr, cq, lane);
        float4 b4 = ld4(b + gelem);
        w4.x = b4.x - ax.x; w4.y = b4.y - ax.y; w4.z = b4.z - ax.z; w4.w = b4.w - ax.w;
        float s = wave_reduce(dot4(w4, w4));
        if (lane == 0) red[16][wv] = s;
        __syncthreads();
        st4(&wt[lr][cq], w4);                 // wt <- r for next pre0
        if (t == 16) { float acc=0.f;
          #pragma unroll
          for (int q=0;q<16;++q) acc += red[16][q]; stc(&pdA[16*NB+blk], acc); }
        if (lr == 0) { float* er = E + (rp^1)*ESZ + ((blk<<1)<<10);
                       stc64(er+cq, w4.x, w4.y); stc64(er+cq+2, w4.z, w4.w); }
        if (lr == 3) { float* er = E + (rp^1)*ESZ + (((blk<<1)+1)<<10);
                       stc64(er+cq, w4.x, w4.y); stc64(er+cq+2, w4.z, w4.w); }
        gridbar(arrive, gen, pdA, pdH, bid++, blk, t, wv, lane, 0, 1);
        rp ^= 1;
      }
    }
  }
}

extern "C" void kernel_launch(void* const* d_in, const int* in_sizes, int n_in,
                              void* d_out, int out_size, void* d_ws, size_t ws_size,
                              hipStream_t stream) {
  const float* b     = (const float*)d_in[0];   // source
  const float* guess = (const float*)d_in[1];   // initial guess
  float* x  = (float*)d_out;
  float* ws = (float*)d_ws;

  float* E    = ws;                        // 2 * ESZ floats (edge double buffer)
  float* pdA  = ws + 2*ESZ;                // KMAX*NB partials
  float* pdH  = pdA + KMAX*NB;             // 32 (reduced sums)
  int*   barm = (int*)(pdH + 32);          // arrive[NB*FS] + gen

  hipMemsetAsync(barm, 0, (NB*FLAG_STRIDE + 16)*sizeof(int), stream);

  k_gmres<<<NB, TPB, 0, stream>>>(b, guess, x, E, pdA, pdH,
                                  barm, barm + NB*FLAG_STRIDE);
}

// Round 8
// 929.278 us; speedup vs baseline: 1.5596x; 1.5596x over previous
//
#include <hip/hip_runtime.h>
#include <math.h>

// Restarted GMRES(16), 4 cycles, Helmholtz (-lap + 0.3) on 1024x1024 periodic fp32.
// Round 8: fix the silent scratch-spill (rounds 3-7 ran with VGPR cap 64 while the
// basis vc[16] alone needs 64 -> whole basis spilled; 2-3 GB/solve of scratch
// traffic). __launch_bounds__(1024,1) -> 128-VGPR cap; halo-V history moved to LDS
// (hvL, own-slots only); red/M union keeps LDS at ~159 KB (1 block/CU).
// Structure/numerics otherwise identical to round 7 (one barrier per Arnoldi step).

#define NGRID 1024
#define NE (NGRID*NGRID)
#define NB 256            // blocks = CUs
#define TPB 1024          // 16 waves
#define RST 16
#define KMAX 17
#define NCYC 4
#define FLAG_STRIDE 16
#define ESZ (NB*2*NGRID)  // floats per edge-buffer parity

__device__ __forceinline__ float4 ld4(const float* p){return *reinterpret_cast<const float4*>(p);}
__device__ __forceinline__ void st4(float* p, float4 v){*reinterpret_cast<float4*>(p)=v;}
__device__ __forceinline__ float dot4(float4 a,float4 b){return a.x*b.x+a.y*b.y+a.z*b.z+a.w*b.w;}

// IC-coherent accesses (relaxed agent-scope atomics)
__device__ __forceinline__ float ldc(const float* p){
  return __hip_atomic_load(p, __ATOMIC_RELAXED, __HIP_MEMORY_SCOPE_AGENT);
}
__device__ __forceinline__ void stc(float* p, float v){
  __hip_atomic_store(p, v, __ATOMIC_RELAXED, __HIP_MEMORY_SCOPE_AGENT);
}
__device__ __forceinline__ int ldci(const int* p){
  return __hip_atomic_load(p, __ATOMIC_RELAXED, __HIP_MEMORY_SCOPE_AGENT);
}
__device__ __forceinline__ void stci(int* p, int v){
  __hip_atomic_store(p, v, __ATOMIC_RELAXED, __HIP_MEMORY_SCOPE_AGENT);
}
__device__ __forceinline__ void stc64(float* p, float a, float b){
  unsigned long long v = ((unsigned long long)__float_as_uint(b) << 32)
                       | (unsigned long long)__float_as_uint(a);
  __hip_atomic_store(reinterpret_cast<unsigned long long*>(p), v,
                     __ATOMIC_RELAXED, __HIP_MEMORY_SCOPE_AGENT);
}
__device__ __forceinline__ float2 ldc64(const float* p){
  unsigned long long v = __hip_atomic_load(reinterpret_cast<const unsigned long long*>(p),
                                           __ATOMIC_RELAXED, __HIP_MEMORY_SCOPE_AGENT);
  return make_float2(__uint_as_float((unsigned)v), __uint_as_float((unsigned)(v>>32)));
}

__device__ __forceinline__ float wave_reduce(float s){
  #pragma unroll
  for(int off=32; off; off>>=1) s += __shfl_down(s,off);
  return s;
}
__device__ __forceinline__ float col_reduce256(const float* col, int lane){
  int b4i = lane*4;
  float s = (ldc(col+b4i) + ldc(col+b4i+1)) + (ldc(col+b4i+2) + ldc(col+b4i+3));
  return wave_reduce(s);
}

// grid barrier with in-barrier central reduce (block 0 reduces partial columns
// while the others would be idle polling anyway).
__device__ __forceinline__ void gridbar(int* arrive, int* gen,
                                        const float* pdA, float* pdH,
                                        int bar_id, int blk, int t, int wv, int lane,
                                        int nc, int donorm){
  __syncthreads();   // per-wave vmcnt drain: all our stc's are at IC before flag
  if (blk == 0) {
    if (t > 0 && t < NB) {
      while (ldci(&arrive[t*FLAG_STRIDE]) < bar_id) __builtin_amdgcn_s_sleep(2);
    }
    __syncthreads();
    for (int c = wv; c < nc; c += 16) {
      float s = col_reduce256(pdA + c*NB, lane);
      if (lane == 0) stc(&pdH[c], s);
    }
    if (donorm && wv == 15) {
      float s = col_reduce256(pdA + 16*NB, lane);
      if (lane == 0) stc(&pdH[16], s);
    }
    __syncthreads();
    if (t == 0) stci(gen, bar_id);
  } else {
    if (t == 0) {
      stci(&arrive[blk*FLAG_STRIDE], bar_id);
      while (ldci(gen) < bar_id) __builtin_amdgcn_s_sleep(2);
    }
    __syncthreads();
  }
}

// stencil over LDS tile + LDS halo rows; lf/rt via shfl of raw center values.
__device__ __forceinline__ float4 stencil2(float4 raw, float4 c, float inv,
                                           const float (*wt)[NGRID],
                                           const float* hup, const float* hdn,
                                           int lr, int cq, int lane){
  float4 a, d;
  if (lr == 0) a = ld4(hup + cq);           else a = ld4(&wt[lr-1][cq]);
  if (lr == 3) d = ld4(hdn + cq);           else d = ld4(&wt[lr+1][cq]);
  float lf = __shfl_up(raw.w, 1);
  float rt = __shfl_down(raw.x, 1);
  if (lane == 0)  lf = wt[lr][(cq + NGRID-1) & (NGRID-1)];
  if (lane == 63) rt = wt[lr][(cq + 4) & (NGRID-1)];
  lf *= inv; rt *= inv;
  a.x*=inv; a.y*=inv; a.z*=inv; a.w*=inv;
  d.x*=inv; d.y*=inv; d.z*=inv; d.w*=inv;
  float4 o;
  o.x = 0.3f*c.x - ((a.x + d.x + lf  + c.y) - 4.0f*c.x);
  o.y = 0.3f*c.y - ((a.y + d.y + c.x + c.z) - 4.0f*c.y);
  o.z = 0.3f*c.z - ((a.z + d.z + c.y + c.w) - 4.0f*c.z);
  o.w = 0.3f*c.w - ((a.w + d.w + c.z + rt ) - 4.0f*c.w);
  return o;
}

// plain global stencil (cycle-0 residual on pristine guess)
__device__ __forceinline__ float4 stencil_g(const float* __restrict__ u,
                                            float4 c, int gi, int cq){
  const float* up = u + (((gi+NGRID-1)&(NGRID-1))<<10);
  const float* dn = u + (((gi+1)&(NGRID-1))<<10);
  float4 a = ld4(up+cq), d = ld4(dn+cq);
  float lf = u[(gi<<10)|((cq+NGRID-1)&(NGRID-1))];
  float rt = u[(gi<<10)|((cq+4)&(NGRID-1))];
  float4 o;
  o.x = 0.3f*c.x - ((a.x + d.x + lf  + c.y) - 4.0f*c.x);
  o.y = 0.3f*c.y - ((a.y + d.y + c.x + c.z) - 4.0f*c.y);
  o.z = 0.3f*c.z - ((a.z + d.z + c.y + c.w) - 4.0f*c.z);
  o.w = 0.3f*c.w - ((a.w + d.w + c.z + rt ) - 4.0f*c.w);
  return o;
}

__global__ __launch_bounds__(TPB, 1) void k_gmres(
    const float* __restrict__ b, const float* __restrict__ guess,
    float* __restrict__ x, float* __restrict__ E,
    float* __restrict__ pdA, float* __restrict__ pdH,
    int* __restrict__ arrive, int* __restrict__ gen)
{
  const int t = threadIdx.x, blk = blockIdx.x;
  const int lr = t >> 8;                 // local row 0..3
  const int cq = (t & 255) << 2;         // col of this thread's 4 elems
  const int gi = blk*4 + lr;
  const int gelem = (gi<<10) + cq;
  const int lane = t & 63, wv = t >> 6;
  const int hcol = (t & 511) << 1;       // this thread's 2 halo cols
  const bool isup = (t < 512);           // owns up-halo (else dn-halo)
  const int side = isup ? 0 : 1;

  __shared__ float wt[4][NGRID];         // 16 KB staging tile
  __shared__ float hrow[2][NGRID];       // raw halo rows: [0]=up, [1]=dn
  __shared__ float hvL[RST][2][NGRID];   // 128 KB halo-V history (own slots only)
  __shared__ union { float red[KMAX][16]; float M[RST][RST+1]; } u;
  __shared__ float sH[KMAX], sC[KMAX];
  __shared__ float G[KMAX][KMAX];
  __shared__ float Hm[KMAX][RST];
  __shared__ float yv[RST];
  __shared__ float sBeta, sInv;

  float4 x4, w4;
  float4 vcr[RST];
  float2 hx;                             // halo-x (2 regs)
  int bid = 1, rp = 0;

  const int uprow = (((blk+NB-1)&(NB-1))<<1) + 1;   // neighbor-above's lr3 row
  const int dnrow = (((blk+1)&(NB-1))<<1);          // neighbor-below's lr0 row
  float* hvp = &hvL[0][side][hcol];                 // stride 2*NGRID per k

  // ---------------- P_init (cycle 0 residual, pristine inputs, plain loads) ----
  x4 = ld4(guess + gelem);
  {
    int hrg = isup ? ((blk*4 + NGRID-1)&(NGRID-1)) : ((blk*4 + 4)&(NGRID-1));
    hx.x = guess[(hrg<<10) + hcol];
    hx.y = guess[(hrg<<10) + hcol + 1];
  }
  {
    float4 ax = stencil_g(guess, x4, gi, cq);
    float4 b4 = ld4(b + gelem);
    w4.x = b4.x - ax.x; w4.y = b4.y - ax.y; w4.z = b4.z - ax.z; w4.w = b4.w - ax.w;
    st4(&wt[lr][cq], w4);                       // wt <- r (pre0's stencil input)
    float s = wave_reduce(dot4(w4, w4));
    if (lane == 0) u.red[16][wv] = s;
    __syncthreads();
    if (t == 16) {
      float acc = 0.f;
      #pragma unroll
      for (int q = 0; q < 16; ++q) acc += u.red[16][q];
      stc(&pdA[16*NB + blk], acc);
    }
    if (lr == 0) { float* er = E + (rp^1)*ESZ + ((blk<<1)<<10);
                   stc64(er+cq, w4.x, w4.y); stc64(er+cq+2, w4.z, w4.w); }
    if (lr == 3) { float* er = E + (rp^1)*ESZ + (((blk<<1)+1)<<10);
                   stc64(er+cq, w4.x, w4.y); stc64(er+cq+2, w4.z, w4.w); }
    gridbar(arrive, gen, pdA, pdH, bid++, blk, t, wv, lane, 0, 1);
    rp ^= 1;
  }

  #pragma unroll 1
  for (int cyc = 0; cyc < NCYC; ++cyc) {
    // ---------------- P_pre0: beta, v0 = r/beta, w = A(v0), first dots ----------
    {
      float pn16 = (t == 0) ? ldc(&pdH[16]) : 0.f;
      float2 hw = ldc64((isup ? (E + rp*ESZ + (uprow<<10))
                              : (E + rp*ESZ + (dnrow<<10))) + hcol);  // r edges
      for (int q = t; q < KMAX*KMAX; q += TPB) ((float*)G)[q] = 0.f;
      for (int q = t; q < KMAX*RST;  q += TPB) ((float*)Hm)[q] = 0.f;
      __syncthreads();
      if (t == 0) {
        float beta = sqrtf(pn16);
        sBeta = beta; sInv = 1.0f/(beta + 1e-12f); G[0][0] = 1.0f;
      }
      __syncthreads();
      float inv = sInv;
      vcr[0].x = w4.x*inv; vcr[0].y = w4.y*inv; vcr[0].z = w4.z*inv; vcr[0].w = w4.w*inv;
      hvp[0] = hw.x*inv; hvp[1] = hw.y*inv;
      hrow[side][hcol]   = hw.x;                          // raw halo r
      hrow[side][hcol+1] = hw.y;
      __syncthreads();
      float4 nw = stencil2(w4, vcr[0], inv, wt, hrow[0], hrow[1], lr, cq, lane);
      w4 = nw;
      { float s = wave_reduce(dot4(vcr[0], w4)); if (lane == 0) u.red[0][wv] = s; }
      { float s = wave_reduce(dot4(w4, w4));     if (lane == 0) u.red[16][wv] = s; }
      __syncthreads();
      if (t == 0) { float acc=0.f;
        #pragma unroll
        for (int q=0;q<16;++q) acc += u.red[0][q];  stc(&pdA[0*NB+blk], acc); }
      if (t == 16){ float acc=0.f;
        #pragma unroll
        for (int q=0;q<16;++q) acc += u.red[16][q]; stc(&pdA[16*NB+blk], acc); }
      if (lr == 0) { float* er = E + (rp^1)*ESZ + ((blk<<1)<<10);
                     stc64(er+cq, w4.x, w4.y); stc64(er+cq+2, w4.z, w4.w); }
      if (lr == 3) { float* er = E + (rp^1)*ESZ + (((blk<<1)+1)<<10);
                     stc64(er+cq, w4.x, w4.y); stc64(er+cq+2, w4.z, w4.w); }
      gridbar(arrive, gen, pdA, pdH, bid++, blk, t, wv, lane, 1, 1);
      rp ^= 1;
    }

    // ---------------- steps J = 0..14: one barrier each -------------------------
    #pragma unroll
    for (int J = 0; J < RST-1; ++J) {
      float2 hw = ldc64((isup ? (E + rp*ESZ + (uprow<<10))
                              : (E + rp*ESZ + (dnrow<<10))) + hcol);  // w edges
      if (t <= J)   sH[t]  = ldc(&pdH[t]);
      if (t == 16)  sH[16] = ldc(&pdH[16]);
      __syncthreads();
      if (t < 64) {                         // c = 2 h1 - G h1
        int k = t;
        double h1k = (k <= J) ? (double)sH[k] : 0.0;
        double g1k = 0.0;
        for (int m = 0; m <= J; ++m) g1k += (double)G[k][m]*(double)sH[m];
        double ck = 2.0*h1k - g1k;
        if (k <= J) sC[k] = (float)ck;
      }
      __syncthreads();
      if (t < 64) {                         // hn, inv, Hm col J, G col J+1
        int k = t;
        double h1k = (k <= J) ? (double)sH[k] : 0.0;
        double ck  = (k <= J) ? (double)sC[k] : 0.0;
        double gck = 0.0;
        for (int m = 0; m <= J; ++m) gck += (double)G[k][m]*(double)sC[m];
        double part = ck*(gck - 2.0*h1k);
        #pragma unroll
        for (int off = 32; off; off >>= 1) part += __shfl_xor(part, off);
        double hn2 = (double)sH[16] + part;
        double hn = sqrt(hn2 > 0.0 ? hn2 : 0.0);
        if (k == 0) { sInv = (float)(1.0/(hn + 1e-12)); Hm[J+1][J] = (float)hn; }
        if (k <= J) Hm[k][J] = sC[k];
        if (k <= J) { float gn = (float)((h1k - gck)/hn); G[k][J+1] = gn; G[J+1][k] = gn; }
        if (k == 0) G[J+1][J+1] = 1.0f;
      }
      __syncthreads();
      float inv = sInv;
      float4 w3 = w4;
      #pragma unroll
      for (int k = 0; k <= J; ++k) {
        float ck = sC[k];
        w3.x -= ck*vcr[k].x; w3.y -= ck*vcr[k].y; w3.z -= ck*vcr[k].z; w3.w -= ck*vcr[k].w;
      }
      vcr[J+1].x = w3.x*inv; vcr[J+1].y = w3.y*inv; vcr[J+1].z = w3.z*inv; vcr[J+1].w = w3.w*inv;
      st4(&wt[lr][cq], w3);                 // wt <- w3 (raw)
      float2 w3h = hw;
      #pragma unroll
      for (int k = 0; k <= J; ++k) {
        float ck = sC[k];
        w3h.x -= ck*hvp[k*2*NGRID]; w3h.y -= ck*hvp[k*2*NGRID+1];
      }
      hvp[(J+1)*2*NGRID] = w3h.x*inv; hvp[(J+1)*2*NGRID+1] = w3h.y*inv;
      hrow[side][hcol]   = w3h.x;           // raw halo w3
      hrow[side][hcol+1] = w3h.y;
      __syncthreads();
      float4 nw = stencil2(w3, vcr[J+1], inv, wt, hrow[0], hrow[1], lr, cq, lane);
      w4 = nw;                              // w4 = A(v_{J+1})
      #pragma unroll
      for (int k = 0; k <= J+1; ++k) {
        float s = wave_reduce(dot4(vcr[k], w4));
        if (lane == 0) u.red[k][wv] = s;
      }
      { float s = wave_reduce(dot4(w4, w4)); if (lane == 0) u.red[16][wv] = s; }
      __syncthreads();
      if (t <= J+1) { float acc=0.f;
        #pragma unroll
        for (int q=0;q<16;++q) acc += u.red[t][q];  stc(&pdA[t*NB+blk], acc); }
      if (t == 16)  { float acc=0.f;
        #pragma unroll
        for (int q=0;q<16;++q) acc += u.red[16][q]; stc(&pdA[16*NB+blk], acc); }
      if (lr == 0) { float* er = E + (rp^1)*ESZ + ((blk<<1)<<10);
                     stc64(er+cq, w4.x, w4.y); stc64(er+cq+2, w4.z, w4.w); }
      if (lr == 3) { float* er = E + (rp^1)*ESZ + (((blk<<1)+1)<<10);
                     stc64(er+cq, w4.x, w4.y); stc64(er+cq+2, w4.z, w4.w); }
      gridbar(arrive, gen, pdA, pdH, bid++, blk, t, wv, lane, J+2, 1);
      rp ^= 1;
    }

    // ---------------- P_fin: Hm col 15, solve, x update, residual for next cycle
    {
      const int J = RST-1;  // 15
      if (t <= J)  sH[t]  = ldc(&pdH[t]);
      if (t == 16) sH[16] = ldc(&pdH[16]);
      __syncthreads();
      if (t < 64) {
        int k = t;
        double h1k = (k <= J) ? (double)sH[k] : 0.0;
        double g1k = 0.0;
        for (int m = 0; m <= J; ++m) g1k += (double)G[k][m]*(double)sH[m];
        double ck = 2.0*h1k - g1k;
        if (k <= J) sC[k] = (float)ck;
      }
      __syncthreads();
      if (t < 64) {
        int k = t;
        double h1k = (k <= J) ? (double)sH[k] : 0.0;
        double ck  = (k <= J) ? (double)sC[k] : 0.0;
        double gck = 0.0;
        for (int m = 0; m <= J; ++m) gck += (double)G[k][m]*(double)sC[m];
        double part = ck*(gck - 2.0*h1k);
        #pragma unroll
        for (int off = 32; off; off >>= 1) part += __shfl_xor(part, off);
        double hn2 = (double)sH[16] + part;
        double hn = sqrt(hn2 > 0.0 ? hn2 : 0.0);
        if (k == 0) Hm[J+1][J] = (float)hn;
        if (k <= J) Hm[k][J] = sC[k];
      }
      __syncthreads();
      // 16x16 normal equations
      if (t < 256) {
        int a = t >> 4, bq = t & 15;
        float s = 0.f;
        #pragma unroll
        for (int k = 0; k < KMAX; ++k) s += Hm[k][a]*Hm[k][bq];
        u.M[a][bq] = s + (a == bq ? 1e-12f : 0.0f);
      }
      __syncthreads();
      if (t < RST) u.M[t][RST] = sBeta * Hm[0][t];
      __syncthreads();
      for (int c = 0; c < RST; ++c) {
        if (t == 0) {
          int p = c; float mx = fabsf(u.M[c][c]);
          for (int r = c+1; r < RST; ++r){ float v=fabsf(u.M[r][c]); if (v>mx){mx=v;p=r;} }
          if (p != c) for (int cc = c; cc <= RST; ++cc){ float tmp=u.M[c][cc]; u.M[c][cc]=u.M[p][cc]; u.M[p][cc]=tmp; }
        }
        __syncthreads();
        if (t > c && t < RST) {
          float f = u.M[t][c]/u.M[c][c];
          for (int cc = c; cc <= RST; ++cc) u.M[t][cc] -= f*u.M[c][cc];
        }
        __syncthreads();
      }
      if (t == 0) {
        for (int c = RST-1; c >= 0; --c) {
          float s = u.M[c][RST];
          for (int cc = c+1; cc < RST; ++cc) s -= u.M[c][cc]*yv[cc];
          yv[c] = s/u.M[c][c];
        }
      }
      __syncthreads();
      #pragma unroll
      for (int k = 0; k < RST; ++k) {
        float yk = yv[k];
        x4.x += yk*vcr[k].x; x4.y += yk*vcr[k].y; x4.z += yk*vcr[k].z; x4.w += yk*vcr[k].w;
      }
      st4(x + gelem, x4);

      if (cyc < NCYC-1) {
        // halo-x update (bit-identical to neighbor's x), residual, publish
        #pragma unroll
        for (int k = 0; k < RST; ++k) {
          float yk = yv[k];
          hx.x += yk*hvp[k*2*NGRID]; hx.y += yk*hvp[k*2*NGRID+1];
        }
        st4(&wt[lr][cq], x4);
        hrow[side][hcol]   = hx.x;
        hrow[side][hcol+1] = hx.y;
        __syncthreads();
        float4 ax = stencil2(x4, x4, 1.0f, wt, hrow[0], hrow[1], lr, cq, lane);
        float4 b4 = ld4(b + gelem);
        w4.x = b4.x - ax.x; w4.y = b4.y - ax.y; w4.z = b4.z - ax.z; w4.w = b4.w - ax.w;
        float s = wave_reduce(dot4(w4, w4));
        if (lane == 0) u.red[16][wv] = s;
        __syncthreads();
        st4(&wt[lr][cq], w4);                 // wt <- r for next pre0
        if (t == 16) { float acc=0.f;
          #pragma unroll
          for (int q=0;q<16;++q) acc += u.red[16][q]; stc(&pdA[16*NB+blk], acc); }
        if (lr == 0) { float* er = E + (rp^1)*ESZ + ((blk<<1)<<10);
                       stc64(er+cq, w4.x, w4.y); stc64(er+cq+2, w4.z, w4.w); }
        if (lr == 3) { float* er = E + (rp^1)*ESZ + (((blk<<1)+1)<<10);
                       stc64(er+cq, w4.x, w4.y); stc64(er+cq+2, w4.z, w4.w); }
        gridbar(arrive, gen, pdA, pdH, bid++, blk, t, wv, lane, 0, 1);
        rp ^= 1;
      }
    }
  }
}

extern "C" void kernel_launch(void* const* d_in, const int* in_sizes, int n_in,
                              void* d_out, int out_size, void* d_ws, size_t ws_size,
                              hipStream_t stream) {
  const float* b     = (const float*)d_in[0];   // source
  const float* guess = (const float*)d_in[1];   // initial guess
  float* x  = (float*)d_out;
  float* ws = (float*)d_ws;

  float* E    = ws;                        // 2 * ESZ floats (edge double buffer)
  float* pdA  = ws + 2*ESZ;                // KMAX*NB partials
  float* pdH  = pdA + KMAX*NB;             // 32 (reduced sums)
  int*   barm = (int*)(pdH + 32);          // arrive[NB*FS] + gen

  hipMemsetAsync(barm, 0, (NB*FLAG_STRIDE + 16)*sizeof(int), stream);

  k_gmres<<<NB, TPB, 0, stream>>>(b, guess, x, E, pdA, pdH,
                                  barm, barm + NB*FLAG_STRIDE);
}

// Round 9
// 863.824 us; speedup vs baseline: 1.6777x; 1.0758x over previous
//
#include <hip/hip_runtime.h>
#include <math.h>

// Restarted GMRES(16), 4 cycles, Helmholtz (-lap + 0.3) on 1024x1024 periodic fp32.
// Round 9: single-hop barrier + per-block all-reduce. No central reduce, no gen
// broadcast, no pdH fetch (round 8's three extra IC round-trips per phase). Each
// block: drain -> set own flag -> 256 threads poll 256 distinct flags -> reduce
// the partial-dot columns itself from pdA (parity ping-pong). Everything else
// (register basis vcr[16], LDS halo-V, Gram-CGS2, one phase per Arnoldi step)
// is round 8 unchanged.

#define NGRID 1024
#define NE (NGRID*NGRID)
#define NB 256            // blocks = CUs
#define TPB 1024          // 16 waves
#define RST 16
#define KMAX 17
#define NCYC 4
#define FLAG_STRIDE 16
#define ESZ (NB*2*NGRID)  // floats per edge-buffer parity
#define PDSTRIDE (KMAX*NB)

__device__ __forceinline__ float4 ld4(const float* p){return *reinterpret_cast<const float4*>(p);}
__device__ __forceinline__ void st4(float* p, float4 v){*reinterpret_cast<float4*>(p)=v;}
__device__ __forceinline__ float dot4(float4 a,float4 b){return a.x*b.x+a.y*b.y+a.z*b.z+a.w*b.w;}

// IC-coherent accesses (relaxed agent-scope atomics)
__device__ __forceinline__ float ldc(const float* p){
  return __hip_atomic_load(p, __ATOMIC_RELAXED, __HIP_MEMORY_SCOPE_AGENT);
}
__device__ __forceinline__ void stc(float* p, float v){
  __hip_atomic_store(p, v, __ATOMIC_RELAXED, __HIP_MEMORY_SCOPE_AGENT);
}
__device__ __forceinline__ int ldci(const int* p){
  return __hip_atomic_load(p, __ATOMIC_RELAXED, __HIP_MEMORY_SCOPE_AGENT);
}
__device__ __forceinline__ void stci(int* p, int v){
  __hip_atomic_store(p, v, __ATOMIC_RELAXED, __HIP_MEMORY_SCOPE_AGENT);
}
__device__ __forceinline__ void stc64(float* p, float a, float b){
  unsigned long long v = ((unsigned long long)__float_as_uint(b) << 32)
                       | (unsigned long long)__float_as_uint(a);
  __hip_atomic_store(reinterpret_cast<unsigned long long*>(p), v,
                     __ATOMIC_RELAXED, __HIP_MEMORY_SCOPE_AGENT);
}
__device__ __forceinline__ float2 ldc64(const float* p){
  unsigned long long v = __hip_atomic_load(reinterpret_cast<const unsigned long long*>(p),
                                           __ATOMIC_RELAXED, __HIP_MEMORY_SCOPE_AGENT);
  return make_float2(__uint_as_float((unsigned)v), __uint_as_float((unsigned)(v>>32)));
}

__device__ __forceinline__ float wave_reduce(float s){
  #pragma unroll
  for(int off=32; off; off>>=1) s += __shfl_down(s,off);
  return s;
}
__device__ __forceinline__ float col_reduce256(const float* col, int lane){
  int b4i = lane*4;
  float s = (ldc(col+b4i) + ldc(col+b4i+1)) + (ldc(col+b4i+2) + ldc(col+b4i+3));
  return wave_reduce(s);
}

// single-hop full barrier: drain (syncthreads' vmcnt(0)) -> own flag -> each of
// 256 threads polls one distinct flag line -> syncthreads.
__device__ __forceinline__ void arrive_wait(int* arrive, int bar_id, int blk, int t){
  __syncthreads();   // compiler drains vmcnt per wave before s_barrier
  if (t == 0) stci(&arrive[blk*FLAG_STRIDE], bar_id);
  if (t < NB) {
    while (ldci(&arrive[t*FLAG_STRIDE]) < bar_id) __builtin_amdgcn_s_sleep(2);
  }
  __syncthreads();
}

// stencil over LDS tile + LDS halo rows; lf/rt via shfl of raw center values.
__device__ __forceinline__ float4 stencil2(float4 raw, float4 c, float inv,
                                           const float (*wt)[NGRID],
                                           const float* hup, const float* hdn,
                                           int lr, int cq, int lane){
  float4 a, d;
  if (lr == 0) a = ld4(hup + cq);           else a = ld4(&wt[lr-1][cq]);
  if (lr == 3) d = ld4(hdn + cq);           else d = ld4(&wt[lr+1][cq]);
  float lf = __shfl_up(raw.w, 1);
  float rt = __shfl_down(raw.x, 1);
  if (lane == 0)  lf = wt[lr][(cq + NGRID-1) & (NGRID-1)];
  if (lane == 63) rt = wt[lr][(cq + 4) & (NGRID-1)];
  lf *= inv; rt *= inv;
  a.x*=inv; a.y*=inv; a.z*=inv; a.w*=inv;
  d.x*=inv; d.y*=inv; d.z*=inv; d.w*=inv;
  float4 o;
  o.x = 0.3f*c.x - ((a.x + d.x + lf  + c.y) - 4.0f*c.x);
  o.y = 0.3f*c.y - ((a.y + d.y + c.x + c.z) - 4.0f*c.y);
  o.z = 0.3f*c.z - ((a.z + d.z + c.y + c.w) - 4.0f*c.z);
  o.w = 0.3f*c.w - ((a.w + d.w + c.z + rt ) - 4.0f*c.w);
  return o;
}

// plain global stencil (cycle-0 residual on pristine guess)
__device__ __forceinline__ float4 stencil_g(const float* __restrict__ u,
                                            float4 c, int gi, int cq){
  const float* up = u + (((gi+NGRID-1)&(NGRID-1))<<10);
  const float* dn = u + (((gi+1)&(NGRID-1))<<10);
  float4 a = ld4(up+cq), d = ld4(dn+cq);
  float lf = u[(gi<<10)|((cq+NGRID-1)&(NGRID-1))];
  float rt = u[(gi<<10)|((cq+4)&(NGRID-1))];
  float4 o;
  o.x = 0.3f*c.x - ((a.x + d.x + lf  + c.y) - 4.0f*c.x);
  o.y = 0.3f*c.y - ((a.y + d.y + c.x + c.z) - 4.0f*c.y);
  o.z = 0.3f*c.z - ((a.z + d.z + c.y + c.w) - 4.0f*c.z);
  o.w = 0.3f*c.w - ((a.w + d.w + c.z + rt ) - 4.0f*c.w);
  return o;
}

__global__ __launch_bounds__(TPB, 1) void k_gmres(
    const float* __restrict__ b, const float* __restrict__ guess,
    float* __restrict__ x, float* __restrict__ E,
    float* __restrict__ pdA, int* __restrict__ arrive)
{
  const int t = threadIdx.x, blk = blockIdx.x;
  const int lr = t >> 8;                 // local row 0..3
  const int cq = (t & 255) << 2;         // col of this thread's 4 elems
  const int gi = blk*4 + lr;
  const int gelem = (gi<<10) + cq;
  const int lane = t & 63, wv = t >> 6;
  const int hcol = (t & 511) << 1;       // this thread's 2 halo cols
  const bool isup = (t < 512);           // owns up-halo (else dn-halo)
  const int side = isup ? 0 : 1;

  __shared__ float wt[4][NGRID];         // 16 KB staging tile
  __shared__ float hrow[2][NGRID];       // raw halo rows: [0]=up, [1]=dn
  __shared__ float hvL[RST][2][NGRID];   // 128 KB halo-V history (own slots only)
  __shared__ union { float red[KMAX][16]; float M[RST][RST+1]; } u;
  __shared__ float sH[KMAX], sC[KMAX];
  __shared__ float G[KMAX][KMAX];
  __shared__ float Hm[KMAX][RST];
  __shared__ float yv[RST];
  __shared__ float sBeta, sInv;

  float4 x4, w4;
  float4 vcr[RST];
  float2 hx;
  int bid = 1;

  const int uprow = (((blk+NB-1)&(NB-1))<<1) + 1;   // neighbor-above's lr3 row
  const int dnrow = (((blk+1)&(NB-1))<<1);          // neighbor-below's lr0 row
  float* hvp = &hvL[0][side][hcol];                 // stride 2*NGRID per k

  // ---------------- P_init (phase 0): r = b - A(guess); publish parity 0 -------
  x4 = ld4(guess + gelem);
  {
    int hrg = isup ? ((blk*4 + NGRID-1)&(NGRID-1)) : ((blk*4 + 4)&(NGRID-1));
    hx.x = guess[(hrg<<10) + hcol];
    hx.y = guess[(hrg<<10) + hcol + 1];
  }
  {
    float4 ax = stencil_g(guess, x4, gi, cq);
    float4 b4 = ld4(b + gelem);
    w4.x = b4.x - ax.x; w4.y = b4.y - ax.y; w4.z = b4.z - ax.z; w4.w = b4.w - ax.w;
    st4(&wt[lr][cq], w4);
    float s = wave_reduce(dot4(w4, w4));
    if (lane == 0) u.red[16][wv] = s;
    __syncthreads();
    if (t == 16) {
      float acc = 0.f;
      #pragma unroll
      for (int q = 0; q < 16; ++q) acc += u.red[16][q];
      stc(&pdA[0*PDSTRIDE + 16*NB + blk], acc);
    }
    if (lr == 0) { float* er = E + 0*ESZ + ((blk<<1)<<10);
                   stc64(er+cq, w4.x, w4.y); stc64(er+cq+2, w4.z, w4.w); }
    if (lr == 3) { float* er = E + 0*ESZ + (((blk<<1)+1)<<10);
                   stc64(er+cq, w4.x, w4.y); stc64(er+cq+2, w4.z, w4.w); }
  }

  #pragma unroll 1
  for (int cyc = 0; cyc < NCYC; ++cyc) {
    // ---------------- P_pre0: beta, v0 = r/beta, w = A(v0), first dots ----------
    {
      arrive_wait(arrive, bid, blk, t);
      const int rdp = (bid-1)&1, wrp = bid&1;
      float2 hw = ldc64((isup ? (E + rdp*ESZ + (uprow<<10))
                              : (E + rdp*ESZ + (dnrow<<10))) + hcol);  // r edges
      // local all-reduce: norm column only
      if (wv == 15) {
        float s = col_reduce256(pdA + rdp*PDSTRIDE + 16*NB, lane);
        if (lane == 0) sH[16] = s;
      }
      for (int q = t; q < KMAX*KMAX; q += TPB) ((float*)G)[q] = 0.f;
      for (int q = t; q < KMAX*RST;  q += TPB) ((float*)Hm)[q] = 0.f;
      __syncthreads();
      if (t == 0) {
        float beta = sqrtf(sH[16]);
        sBeta = beta; sInv = 1.0f/(beta + 1e-12f); G[0][0] = 1.0f;
      }
      __syncthreads();
      float inv = sInv;
      vcr[0].x = w4.x*inv; vcr[0].y = w4.y*inv; vcr[0].z = w4.z*inv; vcr[0].w = w4.w*inv;
      hvp[0] = hw.x*inv; hvp[1] = hw.y*inv;
      hrow[side][hcol]   = hw.x;
      hrow[side][hcol+1] = hw.y;
      __syncthreads();
      float4 nw = stencil2(w4, vcr[0], inv, wt, hrow[0], hrow[1], lr, cq, lane);
      w4 = nw;
      { float s = wave_reduce(dot4(vcr[0], w4)); if (lane == 0) u.red[0][wv] = s; }
      { float s = wave_reduce(dot4(w4, w4));     if (lane == 0) u.red[16][wv] = s; }
      __syncthreads();
      if (t == 0) { float acc=0.f;
        #pragma unroll
        for (int q=0;q<16;++q) acc += u.red[0][q];  stc(&pdA[wrp*PDSTRIDE + 0*NB+blk], acc); }
      if (t == 16){ float acc=0.f;
        #pragma unroll
        for (int q=0;q<16;++q) acc += u.red[16][q]; stc(&pdA[wrp*PDSTRIDE + 16*NB+blk], acc); }
      if (lr == 0) { float* er = E + wrp*ESZ + ((blk<<1)<<10);
                     stc64(er+cq, w4.x, w4.y); stc64(er+cq+2, w4.z, w4.w); }
      if (lr == 3) { float* er = E + wrp*ESZ + (((blk<<1)+1)<<10);
                     stc64(er+cq, w4.x, w4.y); stc64(er+cq+2, w4.z, w4.w); }
      ++bid;
    }

    // ---------------- steps J = 0..14: one phase each ---------------------------
    #pragma unroll
    for (int J = 0; J < RST-1; ++J) {
      arrive_wait(arrive, bid, blk, t);
      const int rdp = (bid-1)&1, wrp = bid&1;
      float2 hw = ldc64((isup ? (E + rdp*ESZ + (uprow<<10))
                              : (E + rdp*ESZ + (dnrow<<10))) + hcol);  // w edges
      // local all-reduce: cols 0..J + norm
      const float* rd = pdA + rdp*PDSTRIDE;
      for (int c = wv; c <= J; c += 16) {
        float s = col_reduce256(rd + c*NB, lane);
        if (lane == 0) sH[c] = s;
      }
      if (wv == 15) {
        float s = col_reduce256(rd + 16*NB, lane);
        if (lane == 0) sH[16] = s;
      }
      __syncthreads();
      if (t < 64) {                         // c = 2 h1 - G h1
        int k = t;
        double h1k = (k <= J) ? (double)sH[k] : 0.0;
        double g1k = 0.0;
        for (int m = 0; m <= J; ++m) g1k += (double)G[k][m]*(double)sH[m];
        double ck = 2.0*h1k - g1k;
        if (k <= J) sC[k] = (float)ck;
      }
      __syncthreads();
      if (t < 64) {                         // hn, inv, Hm col J, G col J+1
        int k = t;
        double h1k = (k <= J) ? (double)sH[k] : 0.0;
        double ck  = (k <= J) ? (double)sC[k] : 0.0;
        double gck = 0.0;
        for (int m = 0; m <= J; ++m) gck += (double)G[k][m]*(double)sC[m];
        double part = ck*(gck - 2.0*h1k);
        #pragma unroll
        for (int off = 32; off; off >>= 1) part += __shfl_xor(part, off);
        double hn2 = (double)sH[16] + part;
        double hn = sqrt(hn2 > 0.0 ? hn2 : 0.0);
        if (k == 0) { sInv = (float)(1.0/(hn + 1e-12)); Hm[J+1][J] = (float)hn; }
        if (k <= J) Hm[k][J] = sC[k];
        if (k <= J) { float gn = (float)((h1k - gck)/hn); G[k][J+1] = gn; G[J+1][k] = gn; }
        if (k == 0) G[J+1][J+1] = 1.0f;
      }
      __syncthreads();
      float inv = sInv;
      float4 w3 = w4;
      #pragma unroll
      for (int k = 0; k <= J; ++k) {
        float ck = sC[k];
        w3.x -= ck*vcr[k].x; w3.y -= ck*vcr[k].y; w3.z -= ck*vcr[k].z; w3.w -= ck*vcr[k].w;
      }
      vcr[J+1].x = w3.x*inv; vcr[J+1].y = w3.y*inv; vcr[J+1].z = w3.z*inv; vcr[J+1].w = w3.w*inv;
      st4(&wt[lr][cq], w3);                 // wt <- w3 (raw)
      float2 w3h = hw;
      #pragma unroll
      for (int k = 0; k <= J; ++k) {
        float ck = sC[k];
        w3h.x -= ck*hvp[k*2*NGRID]; w3h.y -= ck*hvp[k*2*NGRID+1];
      }
      hvp[(J+1)*2*NGRID] = w3h.x*inv; hvp[(J+1)*2*NGRID+1] = w3h.y*inv;
      hrow[side][hcol]   = w3h.x;           // raw halo w3
      hrow[side][hcol+1] = w3h.y;
      __syncthreads();
      float4 nw = stencil2(w3, vcr[J+1], inv, wt, hrow[0], hrow[1], lr, cq, lane);
      w4 = nw;                              // w4 = A(v_{J+1})
      #pragma unroll
      for (int k = 0; k <= J+1; ++k) {
        float s = wave_reduce(dot4(vcr[k], w4));
        if (lane == 0) u.red[k][wv] = s;
      }
      { float s = wave_reduce(dot4(w4, w4)); if (lane == 0) u.red[16][wv] = s; }
      __syncthreads();
      if (t <= J+1) { float acc=0.f;
        #pragma unroll
        for (int q=0;q<16;++q) acc += u.red[t][q];  stc(&pdA[wrp*PDSTRIDE + t*NB+blk], acc); }
      if (t == 16)  { float acc=0.f;
        #pragma unroll
        for (int q=0;q<16;++q) acc += u.red[16][q]; stc(&pdA[wrp*PDSTRIDE + 16*NB+blk], acc); }
      if (lr == 0) { float* er = E + wrp*ESZ + ((blk<<1)<<10);
                     stc64(er+cq, w4.x, w4.y); stc64(er+cq+2, w4.z, w4.w); }
      if (lr == 3) { float* er = E + wrp*ESZ + (((blk<<1)+1)<<10);
                     stc64(er+cq, w4.x, w4.y); stc64(er+cq+2, w4.z, w4.w); }
      ++bid;
    }

    // ---------------- P_fin: Hm col 15, solve, x update, next residual ----------
    {
      arrive_wait(arrive, bid, blk, t);
      const int rdp = (bid-1)&1, wrp = bid&1;
      const int J = RST-1;  // 15
      const float* rd = pdA + rdp*PDSTRIDE;
      for (int c = wv; c <= J; c += 16) {
        float s = col_reduce256(rd + c*NB, lane);
        if (lane == 0) sH[c] = s;
      }
      if (wv == 15) {
        float s = col_reduce256(rd + 16*NB, lane);
        if (lane == 0) sH[16] = s;
      }
      __syncthreads();
      if (t < 64) {
        int k = t;
        double h1k = (k <= J) ? (double)sH[k] : 0.0;
        double g1k = 0.0;
        for (int m = 0; m <= J; ++m) g1k += (double)G[k][m]*(double)sH[m];
        double ck = 2.0*h1k - g1k;
        if (k <= J) sC[k] = (float)ck;
      }
      __syncthreads();
      if (t < 64) {
        int k = t;
        double h1k = (k <= J) ? (double)sH[k] : 0.0;
        double ck  = (k <= J) ? (double)sC[k] : 0.0;
        double gck = 0.0;
        for (int m = 0; m <= J; ++m) gck += (double)G[k][m]*(double)sC[m];
        double part = ck*(gck - 2.0*h1k);
        #pragma unroll
        for (int off = 32; off; off >>= 1) part += __shfl_xor(part, off);
        double hn2 = (double)sH[16] + part;
        double hn = sqrt(hn2 > 0.0 ? hn2 : 0.0);
        if (k == 0) Hm[J+1][J] = (float)hn;
        if (k <= J) Hm[k][J] = sC[k];
      }
      __syncthreads();
      // 16x16 normal equations
      if (t < 256) {
        int a = t >> 4, bq = t & 15;
        float s = 0.f;
        #pragma unroll
        for (int k = 0; k < KMAX; ++k) s += Hm[k][a]*Hm[k][bq];
        u.M[a][bq] = s + (a == bq ? 1e-12f : 0.0f);
      }
      __syncthreads();
      if (t < RST) u.M[t][RST] = sBeta * Hm[0][t];
      __syncthreads();
      for (int c = 0; c < RST; ++c) {
        if (t == 0) {
          int p = c; float mx = fabsf(u.M[c][c]);
          for (int r = c+1; r < RST; ++r){ float v=fabsf(u.M[r][c]); if (v>mx){mx=v;p=r;} }
          if (p != c) for (int cc = c; cc <= RST; ++cc){ float tmp=u.M[c][cc]; u.M[c][cc]=u.M[p][cc]; u.M[p][cc]=tmp; }
        }
        __syncthreads();
        if (t > c && t < RST) {
          float f = u.M[t][c]/u.M[c][c];
          for (int cc = c; cc <= RST; ++cc) u.M[t][cc] -= f*u.M[c][cc];
        }
        __syncthreads();
      }
      if (t == 0) {
        for (int c = RST-1; c >= 0; --c) {
          float s = u.M[c][RST];
          for (int cc = c+1; cc < RST; ++cc) s -= u.M[c][cc]*yv[cc];
          yv[c] = s/u.M[c][c];
        }
      }
      __syncthreads();
      #pragma unroll
      for (int k = 0; k < RST; ++k) {
        float yk = yv[k];
        x4.x += yk*vcr[k].x; x4.y += yk*vcr[k].y; x4.z += yk*vcr[k].z; x4.w += yk*vcr[k].w;
      }
      st4(x + gelem, x4);

      if (cyc < NCYC-1) {
        // halo-x update (bit-identical to neighbor's x), residual, publish
        #pragma unroll
        for (int k = 0; k < RST; ++k) {
          float yk = yv[k];
          hx.x += yk*hvp[k*2*NGRID]; hx.y += yk*hvp[k*2*NGRID+1];
        }
        st4(&wt[lr][cq], x4);
        hrow[side][hcol]   = hx.x;
        hrow[side][hcol+1] = hx.y;
        __syncthreads();
        float4 ax = stencil2(x4, x4, 1.0f, wt, hrow[0], hrow[1], lr, cq, lane);
        float4 b4 = ld4(b + gelem);
        w4.x = b4.x - ax.x; w4.y = b4.y - ax.y; w4.z = b4.z - ax.z; w4.w = b4.w - ax.w;
        float s = wave_reduce(dot4(w4, w4));
        if (lane == 0) u.red[16][wv] = s;
        __syncthreads();
        st4(&wt[lr][cq], w4);                 // wt <- r for next pre0
        if (t == 16) { float acc=0.f;
          #pragma unroll
          for (int q=0;q<16;++q) acc += u.red[16][q]; stc(&pdA[wrp*PDSTRIDE + 16*NB+blk], acc); }
        if (lr == 0) { float* er = E + wrp*ESZ + ((blk<<1)<<10);
                       stc64(er+cq, w4.x, w4.y); stc64(er+cq+2, w4.z, w4.w); }
        if (lr == 3) { float* er = E + wrp*ESZ + (((blk<<1)+1)<<10);
                       stc64(er+cq, w4.x, w4.y); stc64(er+cq+2, w4.z, w4.w); }
        ++bid;
      }
    }
  }
}

extern "C" void kernel_launch(void* const* d_in, const int* in_sizes, int n_in,
                              void* d_out, int out_size, void* d_ws, size_t ws_size,
                              hipStream_t stream) {
  const float* b     = (const float*)d_in[0];   // source
  const float* guess = (const float*)d_in[1];   // initial guess
  float* x  = (float*)d_out;
  float* ws = (float*)d_ws;

  float* E    = ws;                        // 2 * ESZ floats (edge double buffer)
  float* pdA  = ws + 2*ESZ;                // 2 * KMAX*NB partials (parity ping-pong)
  int*   barm = (int*)(pdA + 2*PDSTRIDE);  // arrive[NB*FS]

  hipMemsetAsync(barm, 0, NB*FLAG_STRIDE*sizeof(int), stream);

  k_gmres<<<NB, TPB, 0, stream>>>(b, guess, x, E, pdA, barm);
}